// Round 5
// baseline (255.410 us; speedup 1.0000x reference)
//
#include <hip/hip_runtime.h>

#define MTOT 16384        // 8*2048 tokens
#define NFEAT 512         // out features
#define KTOT 4608         // 512 inputs * 9 segments

typedef float f32x4 __attribute__((ext_vector_type(4)));
typedef short s16x8 __attribute__((ext_vector_type(8)));

__device__ __forceinline__ int div9(int c) { return (c * 7282) >> 16; }  // exact for 0 <= c < 32768

#define GLDS(GP, LP) __builtin_amdgcn_global_load_lds( \
    (const __attribute__((address_space(1))) void*)(GP), \
    (__attribute__((address_space(3))) void*)(LP), 16, 0, 0)

// branchless decode: one code byte -> 8 bf16 one-hot fragment
__device__ __forceinline__ s16x8 decode_frag(unsigned code) {
  unsigned nb0 = code & 15u, nb1 = code >> 4;
  unsigned p0 = nb0 - 1u, p1 = nb1 - 1u;  // wraps to 0xFFFFFFFF when nb==0
  unsigned long long v0 = (nb0 ? 0x3F80ull : 0ull) << ((p0 & 3u) << 4);
  unsigned long long v1 = (nb1 ? 0x3F80ull : 0ull) << ((p1 & 3u) << 4);
  unsigned long long lo = (p0 < 4u ? v0 : 0ull) | (p1 < 4u ? v1 : 0ull);
  unsigned long long hi = (p0 < 4u ? 0ull : v0) | (p1 < 4u ? 0ull : v1);
  union { unsigned long long q[2]; s16x8 v; } u;
  u.q[0] = lo; u.q[1] = hi;
  return u.v;
}

// ---------------- fused prep: bx<2048 -> build_b, else build_codes ----------------
// codeT layout (verified R2): within each 64-token block, byte for token m_local is
// at offset (m_local&15)*4 + (m_local>>4) -- the 4 bytes for rows {lm, 16+lm,
// 32+lm, 48+lm} are contiguous.
__global__ __launch_bounds__(256) void prep(const float* __restrict__ x,
                                            const float* __restrict__ coeffs,
                                            unsigned char* __restrict__ codeT,
                                            unsigned short* __restrict__ Bmat) {
  __shared__ unsigned char segt[64][68];
  const int bx = blockIdx.x;
  const int tid = threadIdx.x;
  if (bx < 2048) {
    // ---- build_b: coeffs -> Bmat[i][k] bf16, k = j*9+s ----
    const int i = bx >> 2, q = bx & 3;
    const float* cb = coeffs + (size_t)i * 6144;
#pragma unroll
    for (int p = 0; p < 5; ++p) {
      int kl = p * 256 + tid;
      if (kl < 1152) {
        int k = q * 1152 + kl;
        int j = div9(k), s = k - j * 9;
        float v = cb[j * 12 + s] + cb[j * 12 + s + 1] + cb[j * 12 + s + 2];
        unsigned u = __float_as_uint(v);
        unsigned rn = (u + 0x7FFFu + ((u >> 16) & 1u)) >> 16;  // RNE f32->bf16
        Bmat[(size_t)i * KTOT + k] = (unsigned short)rn;
      }
    }
  } else {
    // ---- build_codes: x -> codeT[g][m], 64 tokens x 64 inputs per block ----
    const int bb = bx - 2048;
    const int mt = bb >> 3;   // 0..255
    const int jt = bb & 7;    // 0..7
    const int m0 = mt * 64;
    const float4* x4 = (const float4*)x;
    const float T1 = (float)(1.0/9.0), T2 = (float)(2.0/9.0), T3 = (float)(3.0/9.0),
                T4 = (float)(4.0/9.0), T5 = (float)(5.0/9.0), T6 = (float)(6.0/9.0),
                T7 = (float)(7.0/9.0), T8 = (float)(8.0/9.0);
#pragma unroll
    for (int it = 0; it < 4; ++it) {
      int f = it * 256 + tid;
      int m = f >> 4, jq = f & 15;
      float4 v = x4[(size_t)(m0 + m) * 128 + jt * 16 + jq];
      uchar4 sv;
      { float xv = v.x; sv.x = (unsigned char)((xv>=T1)+(xv>=T2)+(xv>=T3)+(xv>=T4)+(xv>=T5)+(xv>=T6)+(xv>=T7)+(xv>=T8)); }
      { float xv = v.y; sv.y = (unsigned char)((xv>=T1)+(xv>=T2)+(xv>=T3)+(xv>=T4)+(xv>=T5)+(xv>=T6)+(xv>=T7)+(xv>=T8)); }
      { float xv = v.z; sv.z = (unsigned char)((xv>=T1)+(xv>=T2)+(xv>=T3)+(xv>=T4)+(xv>=T5)+(xv>=T6)+(xv>=T7)+(xv>=T8)); }
      { float xv = v.w; sv.w = (unsigned char)((xv>=T1)+(xv>=T2)+(xv>=T3)+(xv>=T4)+(xv>=T5)+(xv>=T6)+(xv>=T7)+(xv>=T8)); }
      *(uchar4*)&segt[m][jq * 4] = sv;
    }
    __syncthreads();
#pragma unroll
    for (int p = 0; p < 5; ++p) {
      int u = p * 256 + tid;
      if (u < 1152) {
        int gl = u >> 4, mq = u & 15;
        int c0 = jt * 576 + gl * 8;
        int j0 = div9(c0), j1 = div9(c0 + 7);
        int j0l = j0 - jt * 64, j1l = j1 - jt * 64;
        uchar4 ob;
        unsigned char* pb = (unsigned char*)&ob;
#pragma unroll
        for (int c = 0; c < 4; ++c) {
          int m = mq + c * 16;   // byte c covers row mq + c*16 (row-of-16 major)
          int s0 = segt[m][j0l];
          int pos0 = j0 * 9 + s0 - c0;
          unsigned code = (pos0 >= 0 && pos0 < 8) ? (unsigned)(pos0 + 1) : 0u;
          if (j1 != j0) {
            int s1 = segt[m][j1l];
            int pos1 = j1 * 9 + s1 - c0;
            if (pos1 < 8) code |= (unsigned)(pos1 + 1) << 4;
          }
          pb[c] = (unsigned char)code;
        }
        *(uchar4*)(codeT + (size_t)(jt * 72 + gl) * MTOT + m0 + mq * 4) = ob;
      }
    }
  }
}

// ---------------- main: one-hot bf16 MFMA GEMM, split-K for 4 waves/SIMD ----------------
// Geometry (R5): wave = 32m x 128n x K/2 (split-K). Block = 4 waves
// {m-half mh} x {K-half kh} over a 64m x 128n tile. Grid 1024 -> 4 blocks/CU,
// 16 waves/CU = 4 waves/SIMD (2x R0's TLP; all pipe TOTALS identical to R0:
// LDS 2.36 GB, decode 590k frags, MFMA count same). BK=32 (one MFMA-K/step).
// LDS: 2 kh-panels x 2 slots x 8 KB = 32 KB/block. K-halves combine via LDS.
__global__ __launch_bounds__(256, 4) void kan_gemm(const unsigned char* __restrict__ codeT,
                                                   const unsigned short* __restrict__ Bmat,
                                                   float* __restrict__ out) {
  __shared__ __align__(16) short Blds[2][2][4096];  // [kh][slot][8KB], 32KB total
  const int tid = threadIdx.x;
  const int lane = tid & 63;
  const int wid = tid >> 6;      // 0..3
  const int mh = wid & 1;        // m-half
  const int kh = wid >> 1;       // K-half
  const int lm = lane & 15;
  const int lq = lane >> 4;
  const int bx = blockIdx.x;
  const int mt = bx >> 2;        // 0..255
  const int nt = bx & 3;         // 0..3 (fixed per XCD at grid 1024 -> L2-resident B slice)
  const int m0 = mt * 64, n0 = nt * 128;

  // B staging: wave stages frags ns = mh*4 + c (c=0..3) of its kh panel.
  // frag ns covers n-rows n0+ns*16..+16, k-cols (this tile's 32).
  const unsigned short* gB0 = Bmat + (size_t)(n0 + (mh * 4 + 0) * 16 + lm) * KTOT + kh * 2304 + lq * 8;
  const unsigned short* gB1 = Bmat + (size_t)(n0 + (mh * 4 + 1) * 16 + lm) * KTOT + kh * 2304 + lq * 8;
  const unsigned short* gB2 = Bmat + (size_t)(n0 + (mh * 4 + 2) * 16 + lm) * KTOT + kh * 2304 + lq * 8;
  const unsigned short* gB3 = Bmat + (size_t)(n0 + (mh * 4 + 3) * 16 + lm) * KTOT + kh * 2304 + lq * 8;
  // codes: 1 ushort per lane per step = rows {lm, 16+lm} (bytes 0,1 of the
  // R2 pack at offset lm*4 + mh*2), k-group g = kh*288 + t*4 + lq.
  const unsigned char* gCp = codeT + (size_t)(kh * 288 + lq) * MTOT + m0 + lm * 4 + mh * 2;

  f32x4 acc[2][8] = {};
  s16x8 af[2];
  unsigned crQ[2];

#define CRLOAD(SET) do { \
    crQ[SET] = *(const unsigned short*)gCp; gCp += (size_t)4 * MTOT; } while (0)

#define ISSUE_B(SLOT) do { \
    short* base = &Blds[kh][SLOT][0] + mh * 2048; \
    GLDS(gB0, base);        GLDS(gB1, base + 512);  \
    GLDS(gB2, base + 1024); GLDS(gB3, base + 1536); \
    gB0 += 32; gB1 += 32; gB2 += 32; gB3 += 32; } while (0)

#define DECODE(SET) do { \
    af[0] = decode_frag(crQ[SET] & 255u); \
    af[1] = decode_frag((crQ[SET] >> 8) & 255u); } while (0)

#define COMPUTE(SLOT) do { \
    __builtin_amdgcn_s_setprio(1); \
    _Pragma("unroll") \
    for (int ns = 0; ns < 8; ++ns) { \
      s16x8 bf = *(const s16x8*)&Blds[kh][SLOT][ns * 512 + lane * 8]; \
      acc[0][ns] = __builtin_amdgcn_mfma_f32_16x16x32_bf16(af[0], bf, acc[0][ns], 0, 0, 0); \
      acc[1][ns] = __builtin_amdgcn_mfma_f32_16x16x32_bf16(af[1], bf, acc[1][ns], 0, 0, 0); \
    } \
    __builtin_amdgcn_s_setprio(0); } while (0)

#define VWAIT(N) asm volatile("s_waitcnt vmcnt(" #N ")" ::: "memory")
#define FENCE()  asm volatile("" ::: "memory")
#define BAR()    __builtin_amdgcn_s_barrier()

  // ---- prologue: steps 0,1 in flight (5 VMEM ops each: 1 code + 4 gload_lds) ----
  CRLOAD(0); ISSUE_B(0); FENCE();
  CRLOAD(1); ISSUE_B(1); FENCE();

  // ---- main loop: 72 steps of 32k. Steady in-flight = 10 ops (2 steps).
  // VWAIT(5) forces step t's group {code(t), B(t)}; consume between barriers;
  // refill after BAR#2 (slot t&1 is free: all waves have read it).
#pragma unroll 1
  for (int t = 0; t < 70; ++t) {
    const int set = t & 1;
    VWAIT(5); BAR();
    DECODE(set);
    COMPUTE(set);
    BAR();
    CRLOAD(set); ISSUE_B(set);   // step t+2 -> slot (t+2)&1 = set
  }
  // t = 70 (no refill; 10 in flight at entry)
  VWAIT(5); BAR();
  DECODE(0); COMPUTE(0);
  BAR();
  // t = 71 (5 in flight)
  VWAIT(0); BAR();
  DECODE(1); COMPUTE(1);

  // ---- split-K combine via LDS (idx-major: conflict-free) ----
  BAR();                         // all ds_reads of the final tiles done
  if (kh == 1) {
    float* p = (float*)(&Blds[0][0][0]) + (size_t)mh * 4096;
#pragma unroll
    for (int ms = 0; ms < 2; ++ms)
#pragma unroll
      for (int ns = 0; ns < 8; ++ns)
#pragma unroll
        for (int rg = 0; rg < 4; ++rg)
          p[((ms * 8 + ns) * 4 + rg) * 64 + lane] = acc[ms][ns][rg];
  }
  BAR();
  if (kh == 0) {
    const float* p = (const float*)(&Blds[0][0][0]) + (size_t)mh * 4096;
#pragma unroll
    for (int ms = 0; ms < 2; ++ms)
#pragma unroll
      for (int ns = 0; ns < 8; ++ns) {
        int tok = m0 + mh * 32 + ms * 16 + lq * 4;
        int col = n0 + ns * 16 + lm;
        float* op = out + (size_t)tok * NFEAT + col;
#pragma unroll
        for (int rg = 0; rg < 4; ++rg)
          op[(size_t)rg * NFEAT] = acc[ms][ns][rg] + p[((ms * 8 + ns) * 4 + rg) * 64 + lane];
      }
  }
#undef CRLOAD
#undef ISSUE_B
#undef DECODE
#undef COMPUTE
#undef VWAIT
#undef FENCE
#undef BAR
}

extern "C" void kernel_launch(void* const* d_in, const int* in_sizes, int n_in,
                              void* d_out, int out_size, void* d_ws, size_t ws_size,
                              hipStream_t stream) {
  const float* x = (const float*)d_in[0];        // [16384, 512] f32
  const float* coeffs = (const float*)d_in[1];   // [512, 512, 12] f32
  float* out = (float*)d_out;                    // [16384, 512] f32
  unsigned char* codeT = (unsigned char*)d_ws;                                  // 576*16384 = 9.44 MB
  unsigned short* Bmat = (unsigned short*)((char*)d_ws + (size_t)576 * MTOT);   // 512*4608*2 = 4.72 MB

  prep<<<dim3(4096), dim3(256), 0, stream>>>(x, coeffs, codeT, Bmat);
  kan_gemm<<<dim3(1024), dim3(256), 0, stream>>>(codeT, Bmat, out);
}

// Round 6
// 171.716 us; speedup vs baseline: 1.4874x; 1.4874x over previous
//
#include <hip/hip_runtime.h>

#define MTOT 16384        // 8*2048 tokens
#define NFEAT 512         // out features
#define KTOT 4608         // 512 inputs * 9 segments

typedef float f32x4 __attribute__((ext_vector_type(4)));
typedef short s16x8 __attribute__((ext_vector_type(8)));

__device__ __forceinline__ int div9(int c) { return (c * 7282) >> 16; }  // exact for 0 <= c < 32768

#define GLDS(GP, LP) __builtin_amdgcn_global_load_lds( \
    (const __attribute__((address_space(1))) void*)(GP), \
    (__attribute__((address_space(3))) void*)(LP), 16, 0, 0)

// branchless decode: one code byte -> 8 bf16 one-hot fragment (used to build LUT)
__device__ __forceinline__ s16x8 decode_frag(unsigned code) {
  unsigned nb0 = code & 15u, nb1 = code >> 4;
  unsigned p0 = nb0 - 1u, p1 = nb1 - 1u;  // wraps to 0xFFFFFFFF when nb==0
  unsigned long long v0 = (nb0 ? 0x3F80ull : 0ull) << ((p0 & 3u) << 4);
  unsigned long long v1 = (nb1 ? 0x3F80ull : 0ull) << ((p1 & 3u) << 4);
  unsigned long long lo = (p0 < 4u ? v0 : 0ull) | (p1 < 4u ? v1 : 0ull);
  unsigned long long hi = (p0 < 4u ? 0ull : v0) | (p1 < 4u ? 0ull : v1);
  union { unsigned long long q[2]; s16x8 v; } u;
  u.q[0] = lo; u.q[1] = hi;
  return u.v;
}

// ---------------- fused prep: bx<2048 -> build_b, else build_codes ----------------
// codeT layout (verified R2): within each 64-token block, byte for token m_local is
// at offset (m_local&15)*4 + (m_local>>4) -- the 4 bytes for rows {lm, 16+lm,
// 32+lm, 48+lm} are contiguous (one dword per lane).
__global__ __launch_bounds__(256) void prep(const float* __restrict__ x,
                                            const float* __restrict__ coeffs,
                                            unsigned char* __restrict__ codeT,
                                            unsigned short* __restrict__ Bmat) {
  __shared__ unsigned char segt[64][68];
  const int bx = blockIdx.x;
  const int tid = threadIdx.x;
  if (bx < 2048) {
    // ---- build_b: coeffs -> Bmat[i][k] bf16, k = j*9+s ----
    const int i = bx >> 2, q = bx & 3;
    const float* cb = coeffs + (size_t)i * 6144;
#pragma unroll
    for (int p = 0; p < 5; ++p) {
      int kl = p * 256 + tid;
      if (kl < 1152) {
        int k = q * 1152 + kl;
        int j = div9(k), s = k - j * 9;
        float v = cb[j * 12 + s] + cb[j * 12 + s + 1] + cb[j * 12 + s + 2];
        unsigned u = __float_as_uint(v);
        unsigned rn = (u + 0x7FFFu + ((u >> 16) & 1u)) >> 16;  // RNE f32->bf16
        Bmat[(size_t)i * KTOT + k] = (unsigned short)rn;
      }
    }
  } else {
    // ---- build_codes: x -> codeT[g][m], 64 tokens x 64 inputs per block ----
    const int bb = bx - 2048;
    const int mt = bb >> 3;   // 0..255
    const int jt = bb & 7;    // 0..7
    const int m0 = mt * 64;
    const float4* x4 = (const float4*)x;
    const float T1 = (float)(1.0/9.0), T2 = (float)(2.0/9.0), T3 = (float)(3.0/9.0),
                T4 = (float)(4.0/9.0), T5 = (float)(5.0/9.0), T6 = (float)(6.0/9.0),
                T7 = (float)(7.0/9.0), T8 = (float)(8.0/9.0);
#pragma unroll
    for (int it = 0; it < 4; ++it) {
      int f = it * 256 + tid;
      int m = f >> 4, jq = f & 15;
      float4 v = x4[(size_t)(m0 + m) * 128 + jt * 16 + jq];
      uchar4 sv;
      { float xv = v.x; sv.x = (unsigned char)((xv>=T1)+(xv>=T2)+(xv>=T3)+(xv>=T4)+(xv>=T5)+(xv>=T6)+(xv>=T7)+(xv>=T8)); }
      { float xv = v.y; sv.y = (unsigned char)((xv>=T1)+(xv>=T2)+(xv>=T3)+(xv>=T4)+(xv>=T5)+(xv>=T6)+(xv>=T7)+(xv>=T8)); }
      { float xv = v.z; sv.z = (unsigned char)((xv>=T1)+(xv>=T2)+(xv>=T3)+(xv>=T4)+(xv>=T5)+(xv>=T6)+(xv>=T7)+(xv>=T8)); }
      { float xv = v.w; sv.w = (unsigned char)((xv>=T1)+(xv>=T2)+(xv>=T3)+(xv>=T4)+(xv>=T5)+(xv>=T6)+(xv>=T7)+(xv>=T8)); }
      *(uchar4*)&segt[m][jq * 4] = sv;
    }
    __syncthreads();
#pragma unroll
    for (int p = 0; p < 5; ++p) {
      int u = p * 256 + tid;
      if (u < 1152) {
        int gl = u >> 4, mq = u & 15;
        int c0 = jt * 576 + gl * 8;
        int j0 = div9(c0), j1 = div9(c0 + 7);
        int j0l = j0 - jt * 64, j1l = j1 - jt * 64;
        uchar4 ob;
        unsigned char* pb = (unsigned char*)&ob;
#pragma unroll
        for (int c = 0; c < 4; ++c) {
          int m = mq + c * 16;   // byte c covers row mq + c*16 (row-of-16 major)
          int s0 = segt[m][j0l];
          int pos0 = j0 * 9 + s0 - c0;
          unsigned code = (pos0 >= 0 && pos0 < 8) ? (unsigned)(pos0 + 1) : 0u;
          if (j1 != j0) {
            int s1 = segt[m][j1l];
            int pos1 = j1 * 9 + s1 - c0;
            if (pos1 < 8) code |= (unsigned)(pos1 + 1) << 4;
          }
          pb[c] = (unsigned char)code;
        }
        *(uchar4*)(codeT + (size_t)(jt * 72 + gl) * MTOT + m0 + mq * 4) = ob;
      }
    }
  }
}

// ---------------- main: one-hot bf16 MFMA GEMM, split-K/2 + LDS LUT decode ----------------
// Geometry (R6): wave = 64m x 128n x K/2. Block = 4 waves {mh} x {kh} covering
// 128m x 128n. Grid 512 -> 2 blocks/CU, 8 waves/CU = 2 waves/SIMD (R0's proven
// TLP). BK=64 cadence (R5's failure was BK=32, not split-K). Pipes: LDS B-read
// 1.18 GB (~23us) + stage 11 + LUT 0.6 GB (~12) ; VALU ~11 (LUT kills decode);
// MFMA 37 = max pipe. One __syncthreads per K-tile, R0-style double buffer.
__global__ __launch_bounds__(256, 2) void kan_gemm(const unsigned char* __restrict__ codeT,
                                                   const unsigned short* __restrict__ Bmat,
                                                   float* __restrict__ out) {
  __shared__ __align__(16) short Blds[2][2][8192];  // [kh][slot][16KB] = 64 KB
  __shared__ __align__(16) short lut[256 * 8];      // 4 KB: code byte -> 16B fragment
  const int tid = threadIdx.x;
  const int lane = tid & 63;
  const int wid = tid >> 6;      // 0..3
  const int mh = wid & 1;        // m-half (which 64-token block)
  const int kh = wid >> 1;       // K-half
  const int lm = lane & 15;
  const int lq = lane >> 4;
  const int bx = blockIdx.x;
  const int mt = bx >> 2;        // 0..127
  const int nt = bx & 3;         // 0..3
  const int m0 = mt * 128, n0 = nt * 128;
  const int mb64 = m0 + mh * 64; // this wave's 64-token block base

  // build decode LUT (all 256 threads, one entry each)
  { s16x8 v = decode_frag((unsigned)tid); *(s16x8*)&lut[tid * 8] = v; }

  // B staging: wave (mh,kh) stages frags f = mh*8 + c (c=0..7) of its kh panel.
  // f = ns*2+ks -> ns = mh*4 + (c>>1), ks = c&1.
  // addr(c) = Bmat[(n0 + ns*16 + lm)*KTOT + kh*2304 + t*64 + ks*32 + lq*8]
  const unsigned short* gBp = Bmat + (size_t)(n0 + mh * 64 + lm) * KTOT + kh * 2304 + lq * 8;
  // codes: dword per (k-group g, lane lm) covering rows {lm,16+lm,32+lm,48+lm};
  // per tile need g = tbase + {lq, 4+lq}, tbase = kh*288 + t*8.
  const unsigned* gC0 = (const unsigned*)(codeT + (size_t)(kh * 288 + lq) * MTOT + mb64) + lm;
  const unsigned* gC1 = (const unsigned*)(codeT + (size_t)(kh * 288 + 4 + lq) * MTOT + mb64) + lm;

  f32x4 acc[4][8] = {};   // 128 VGPRs: 64m x 128n per wave
  s16x8 af[8];
  unsigned crQ[2][2];

#define CRLOAD(SET) do { \
    crQ[SET][0] = gC0[0]; crQ[SET][1] = gC1[0]; \
    gC0 += 2 * MTOT; gC1 += 2 * MTOT; } while (0)

#define ISSUE_B(SLOT) do { \
    short* dst = &Blds[kh][SLOT][mh * 4096]; \
    GLDS(gBp,                 dst);        \
    GLDS(gBp + 32,            dst + 512);  \
    GLDS(gBp + 16 * KTOT,     dst + 1024); \
    GLDS(gBp + 16 * KTOT + 32, dst + 1536); \
    GLDS(gBp + 32 * KTOT,     dst + 2048); \
    GLDS(gBp + 32 * KTOT + 32, dst + 2560); \
    GLDS(gBp + 48 * KTOT,     dst + 3072); \
    GLDS(gBp + 48 * KTOT + 32, dst + 3584); \
    gBp += 64; } while (0)

#define DECODE(SET) do { \
    _Pragma("unroll") \
    for (int ms = 0; ms < 4; ++ms) { \
      af[ms * 2 + 0] = *(const s16x8*)&lut[((crQ[SET][0] >> (ms * 8)) & 255u) * 8]; \
      af[ms * 2 + 1] = *(const s16x8*)&lut[((crQ[SET][1] >> (ms * 8)) & 255u) * 8]; \
    } } while (0)

#define COMPUTE(SLOT) do { \
    __builtin_amdgcn_s_setprio(1); \
    _Pragma("unroll") \
    for (int ks = 0; ks < 2; ++ks) { \
      s16x8 bf[8]; \
      _Pragma("unroll") \
      for (int ns = 0; ns < 8; ++ns) \
        bf[ns] = *(const s16x8*)&Blds[kh][SLOT][(ns * 2 + ks) * 512 + lane * 8]; \
      _Pragma("unroll") \
      for (int ms = 0; ms < 4; ++ms) \
        _Pragma("unroll") \
        for (int ns = 0; ns < 8; ++ns) \
          acc[ms][ns] = __builtin_amdgcn_mfma_f32_16x16x32_bf16(af[ms * 2 + ks], bf[ns], acc[ms][ns], 0, 0, 0); \
    } \
    __builtin_amdgcn_s_setprio(0); } while (0)

  // ---- prologue: tile 0 staged + codes; sync also publishes the LUT ----
  CRLOAD(0);
  ISSUE_B(0);
  __syncthreads();

  // ---- main loop: 36 tiles, unrolled x2 so all buffer indices are static ----
#pragma unroll 1
  for (int tt = 0; tt < 18; ++tt) {
    // even tile t = 2*tt: consume set/slot 0, prefetch tile t+1 into 1
    ISSUE_B(1); CRLOAD(1);
    DECODE(0);
    COMPUTE(0);
    __syncthreads();
    // odd tile t = 2*tt+1: consume 1, prefetch tile t+2 into 0
    if (tt < 17) { ISSUE_B(0); CRLOAD(0); }
    DECODE(1);
    COMPUTE(1);
    __syncthreads();
  }

  // ---- split-K combine: kh=1 waves publish acc via LDS, kh=0 adds + stores ----
  if (kh == 1) {
    float* p = (float*)(&Blds[0][0][0]) + mh * 8192;   // 32 KB per mh-half
#pragma unroll
    for (int ms = 0; ms < 4; ++ms)
#pragma unroll
      for (int ns = 0; ns < 8; ++ns)
#pragma unroll
        for (int rg = 0; rg < 4; ++rg)
          p[((ms * 8 + ns) * 4 + rg) * 64 + lane] = acc[ms][ns][rg];
  }
  __syncthreads();
  if (kh == 0) {
    const float* p = (const float*)(&Blds[0][0][0]) + mh * 8192;
#pragma unroll
    for (int ms = 0; ms < 4; ++ms)
#pragma unroll
      for (int ns = 0; ns < 8; ++ns) {
        int tok = mb64 + ms * 16 + lq * 4;   // C/D layout: col=lane&15, row=lq*4+rg
        int col = n0 + ns * 16 + lm;
        float* op = out + (size_t)tok * NFEAT + col;
#pragma unroll
        for (int rg = 0; rg < 4; ++rg)
          op[(size_t)rg * NFEAT] = acc[ms][ns][rg] + p[((ms * 8 + ns) * 4 + rg) * 64 + lane];
      }
  }
#undef CRLOAD
#undef ISSUE_B
#undef DECODE
#undef COMPUTE
}

extern "C" void kernel_launch(void* const* d_in, const int* in_sizes, int n_in,
                              void* d_out, int out_size, void* d_ws, size_t ws_size,
                              hipStream_t stream) {
  const float* x = (const float*)d_in[0];        // [16384, 512] f32
  const float* coeffs = (const float*)d_in[1];   // [512, 512, 12] f32
  float* out = (float*)d_out;                    // [16384, 512] f32
  unsigned char* codeT = (unsigned char*)d_ws;                                  // 576*16384 = 9.44 MB
  unsigned short* Bmat = (unsigned short*)((char*)d_ws + (size_t)576 * MTOT);   // 512*4608*2 = 4.72 MB

  prep<<<dim3(4096), dim3(256), 0, stream>>>(x, coeffs, codeT, Bmat);
  kan_gemm<<<dim3(512), dim3(256), 0, stream>>>(codeT, Bmat, out);
}